// Round 13
// baseline (55573.456 us; speedup 1.0000x reference)
//
#include <hip/hip_runtime.h>
#include <hip/hip_bf16.h>
#include <math.h>

// RSSM scan — numpy-realization f32 (frozen numerics), r13: persistent kernel,
// 1024 co-resident blocks (4/CU). Activations via device-scope (AGENT) atomic
// loads/stores -> coherent at LLC, no L2 fences -> weights stay L2-resident.
// Tree barrier, padded reduction LDS. Numeric chains byte-identical to r10.

#define NB 1024
constexpr int KS = 1 << 30;

struct GArg {
  const float* A0; int lda0;
  const float* A1; int lda1;
  int kSplit;
  const float* W; int ldw;
  float* C; int N; int K;             // panel s written at C + s*256*N
};

__device__ __forceinline__ float exp_cr(float x)  { return (float)exp((double)x); }
__device__ __forceinline__ float log_cr(float x)  { return (float)log((double)x); }
__device__ __forceinline__ float tanh_cr(float x) { return (float)tanh((double)x); }
__device__ __forceinline__ float sigmoid_cr(float x) {
  float e = exp_cr(-x);
  float d = __fadd_rn(1.0f, e);
  return __fdiv_rn(1.0f, d);
}

// ---- device-coherent activation accesses (bypass per-XCD L2) ----
__device__ __forceinline__ float ldcc(const float* p) {
  return __hip_atomic_load(p, __ATOMIC_RELAXED, __HIP_MEMORY_SCOPE_AGENT);
}
__device__ __forceinline__ void stcc(float* p, float v) {
  __hip_atomic_store(p, v, __ATOMIC_RELAXED, __HIP_MEMORY_SCOPE_AGENT);
}

// ---- device barrier: per-wave store drain + 2-level arrival tree ----
__device__ __forceinline__ void gbar(unsigned* bar, unsigned* round) {
  asm volatile("s_waitcnt vmcnt(0)" ::: "memory");   // drain this wave's stores
  __syncthreads();
  if (threadIdx.x == 0) {
    unsigned tgt = ++(*round);
    unsigned g = blockIdx.x >> 6;                    // 16 groups of 64
    unsigned v = atomicAdd(&bar[g * 32], 1u);
    if (v == tgt * 64u - 1u) {
      unsigned u = atomicAdd(&bar[512], 1u);
      if (u == tgt * 16u - 1u) atomicAdd(&bar[544], 1u);
    }
    while (__hip_atomic_load(&bar[544], __ATOMIC_RELAXED, __HIP_MEMORY_SCOPE_AGENT) < tgt)
      __builtin_amdgcn_s_sleep(8);
    __builtin_amdgcn_sched_barrier(0);
  }
  __syncthreads();
}

// ---- one 64x64x(384-panel) tile; chains bit-identical to r10 ----
__device__ void gemm_tile(const GArg& G, int s, int n0, int m0,
                          float (*As)[16][68], float (*Bs)[16][68])
{
  int tid = threadIdx.x;
  int tx = tid & 15, ty = tid >> 4;
  int kq = tid & 3,  rr = tid >> 2;

  bool vecOK = ((G.ldw & 3) == 0) && ((G.lda0 & 3) == 0) && ((G.lda1 & 3) == 0)
            && (((G.kSplit & 15) == 0) || (G.kSplit >= G.K));

  float acc[4][4];
  #pragma unroll
  for (int j = 0; j < 4; ++j)
    #pragma unroll
    for (int i = 0; i < 4; ++i) acc[j][i] = 0.0f;

  int nt = (G.K + 15) >> 4;
  int t0 = s * 24, t1 = min(nt, t0 + 24);

  float a[4], w[4];
  int useVec = 0;

  auto stage_load = [&](int kt) {
    int kb = kt * 16;
    useVec = vecOK && (kb + 16 <= G.K);
    if (useVec) {
      int k = kb + kq * 4;
      const float* Ap = (k < G.kSplit)
        ? G.A0 + (size_t)(m0 + rr) * G.lda0 + k
        : G.A1 + (size_t)(m0 + rr) * G.lda1 + (k - G.kSplit);
      #pragma unroll
      for (int i = 0; i < 4; ++i) a[i] = ldcc(Ap + i);          // contiguous k
      float4 wv = *(const float4*)(G.W + (size_t)(n0 + rr) * G.ldw + k);  // cached
      w[0] = wv.x; w[1] = wv.y; w[2] = wv.z; w[3] = wv.w;
    } else {
      int k = kb + tx;
      #pragma unroll
      for (int i = 0; i < 4; ++i) { a[i] = 0.0f; w[i] = 0.0f; }
      if (k < G.K) {
        if (k < G.kSplit) {
          const float* Ap = G.A0 + (size_t)(m0 + ty * 4) * G.lda0 + k;
          #pragma unroll
          for (int i = 0; i < 4; ++i) a[i] = ldcc(Ap + (size_t)i * G.lda0);
        } else {
          const float* Ap = G.A1 + (size_t)(m0 + ty * 4) * G.lda1 + (k - G.kSplit);
          #pragma unroll
          for (int i = 0; i < 4; ++i) a[i] = ldcc(Ap + (size_t)i * G.lda1);
        }
        const float* Wp = G.W + (size_t)(n0 + ty * 4) * G.ldw + k;
        #pragma unroll
        for (int i = 0; i < 4; ++i) w[i] = Wp[(size_t)i * G.ldw];
      }
    }
  };
  auto stage_write = [&](int b) {
    if (useVec) {
      #pragma unroll
      for (int i = 0; i < 4; ++i) {
        As[b][kq * 4 + i][rr] = a[i];    // bank (16kq+4i+rr)%32: 2-way, free
        Bs[b][kq * 4 + i][rr] = w[i];
      }
    } else {
      *(float4*)&As[b][tx][ty * 4] = make_float4(a[0], a[1], a[2], a[3]);
      *(float4*)&Bs[b][tx][ty * 4] = make_float4(w[0], w[1], w[2], w[3]);
    }
  };
  auto compute = [&](int b) {
    #pragma unroll
    for (int kk = 0; kk < 16; ++kk) {
      float4 av = *(const float4*)&As[b][kk][ty * 4];
      float4 bv = *(const float4*)&Bs[b][kk][tx * 4];
      float aa[4] = {av.x, av.y, av.z, av.w};
      float bb[4] = {bv.x, bv.y, bv.z, bv.w};
      #pragma unroll
      for (int j = 0; j < 4; ++j)
        #pragma unroll
        for (int i = 0; i < 4; ++i)
          acc[j][i] = fmaf(aa[j], bb[i], acc[j][i]);   // k-ascending chain
    }
  };

  __syncthreads();                     // prev tile's LDS readers done
  stage_load(t0); stage_write(0); __syncthreads();
  int cur = 0;
  for (int kt = t0; kt < t1; ++kt) {
    if (kt + 1 < t1) {
      stage_load(kt + 1);
      compute(cur);
      stage_write(cur ^ 1);
      __syncthreads();
      cur ^= 1;
    } else compute(cur);
  }

  float* Cp = G.C + (size_t)s * 256 * G.N;
  #pragma unroll
  for (int j = 0; j < 4; ++j) {
    float* cp = &Cp[(size_t)(m0 + ty * 4 + j) * G.N + n0 + tx * 4];
    #pragma unroll
    for (int i = 0; i < 4; ++i) stcc(cp + i, acc[j][i]);
  }
}

__device__ void run3(const GArg& A, int ca, const GArg& B, int cb,
                     const GArg& C, int cc,
                     float (*As)[16][68], float (*Bs)[16][68])
{
  int tot = ca + cb + cc;
  for (int wv = blockIdx.x; wv < tot; wv += NB) {
    const GArg* G; int l;
    if (wv < ca)            { G = &A; l = wv; }
    else if (wv < ca + cb)  { G = &B; l = wv - ca; }
    else                    { G = &C; l = wv - ca - cb; }
    int nbx = G->N >> 6;
    int per = nbx * 4;
    int s = l / per, rem = l % per;
    int mb = rem / nbx, nb = rem % nbx;
    gemm_tile(*G, s, nb * 64, mb * 64, As, Bs);
  }
}

// ---- frozen wave0 pairwise reduction on xs (stride 21, conflict-free) ----
__device__ __forceinline__ void redstats(float (*xs)[21], float* stats) {
  int tid = threadIdx.x, cl = tid & 63;
  __syncthreads();
  if (tid < 64) {
    float r = xs[cl][0];
    #pragma unroll
    for (int i = 1; i < 16; ++i) r = __fadd_rn(r, xs[cl][i]);
    r = __fadd_rn(r, __shfl_xor(r, 1));
    r = __fadd_rn(r, __shfl_xor(r, 2));
    r = __fadd_rn(r, __shfl_xor(r, 4));
    r = __fadd_rn(r, __shfl_xor(r, 8));
    r = __fadd_rn(r, __shfl_xor(r, 16));
    r = __fadd_rn(r, __shfl_xor(r, 32));
    float mean = __fmul_rn(r, 0.0009765625f);
    float d0 = __fsub_rn(xs[cl][0], mean);
    float r2 = __fmul_rn(d0, d0);
    #pragma unroll
    for (int i = 1; i < 16; ++i) {
      float d = __fsub_rn(xs[cl][i], mean);
      r2 = __fadd_rn(r2, __fmul_rn(d, d));
    }
    r2 = __fadd_rn(r2, __shfl_xor(r2, 1));
    r2 = __fadd_rn(r2, __shfl_xor(r2, 2));
    r2 = __fadd_rn(r2, __shfl_xor(r2, 4));
    r2 = __fadd_rn(r2, __shfl_xor(r2, 8));
    r2 = __fadd_rn(r2, __shfl_xor(r2, 16));
    r2 = __fadd_rn(r2, __shfl_xor(r2, 32));
    float var = __fmul_rn(r2, 0.0009765625f);
    float sdv = __fsqrt_rn(__fadd_rn(var, (float)1e-5));
    if (cl == 0) { stats[0] = mean; stats[1] = __fdiv_rn(1.0f, sdv); }
  }
  __syncthreads();
}

template<int S>
__device__ void ln_row(const float* Y, const float* bias, const float* gg,
                       const float* be, float* O, int row,
                       float (*xs)[21], float* stats)
{
  int tid = threadIdx.x;
  int cl = tid & 63, iq = tid >> 6;
  int kb = cl >> 3, j = cl & 7;

  float xv[4];
  #pragma unroll
  for (int q = 0; q < 4; ++q) {
    int i = iq * 4 + q;
    int n = kb * 128 + 8 * i + j;
    size_t idx = (size_t)row * 1024 + n;
    float x = ldcc(Y + idx);
    #pragma unroll
    for (int ss = 1; ss < S; ++ss)
      x = __fadd_rn(x, ldcc(Y + (size_t)ss * 262144 + idx));
    x = __fadd_rn(x, bias[n]);
    xv[q] = x;
    xs[cl][i] = x;
  }
  redstats(xs, stats);
  float mean = stats[0], rstd = stats[1];
  #pragma unroll
  for (int q = 0; q < 4; ++q) {
    int i = iq * 4 + q;
    int n = kb * 128 + 8 * i + j;
    float d = __fsub_rn(xv[q], mean);
    float t = __fmul_rn(__fmul_rn(d, rstd), gg[n]);
    t = __fadd_rn(t, be[n]);
    stcc(O + (size_t)row * 1024 + n, __fmul_rn(t, sigmoid_cr(t)));   // silu
  }
}

__device__ void gru_row(const float* GX, const float* GH, float* H,
                        const float* b_ih, const float* b_hh,
                        const float* g_gn, const float* b_gn,
                        float* out, int t, int row,
                        float (*xs)[21], float* stats)
{
  int tid = threadIdx.x;
  int cl = tid & 63, iq = tid >> 6;
  int kb = cl >> 3, j = cl & 7;

  float hv[4];
  #pragma unroll
  for (int q = 0; q < 4; ++q) {
    int i = iq * 4 + q;
    int n = kb * 128 + 8 * i + j;
    size_t i0 = (size_t)row * 3072 + n;
    #define FOLD3(P, off) __fadd_rn(__fadd_rn(ldcc((P) + (off)), ldcc((P) + 786432 + (off))), ldcc((P) + 1572864 + (off)))
    float xr = __fadd_rn(FOLD3(GX, i0),        b_ih[n]);
    float xu = __fadd_rn(FOLD3(GX, i0 + 1024), b_ih[n + 1024]);
    float xn = __fadd_rn(FOLD3(GX, i0 + 2048), b_ih[n + 2048]);
    float hr = __fadd_rn(FOLD3(GH, i0),        b_hh[n]);
    float hu = __fadd_rn(FOLD3(GH, i0 + 1024), b_hh[n + 1024]);
    float hn = __fadd_rn(FOLD3(GH, i0 + 2048), b_hh[n + 2048]);
    #undef FOLD3
    float r = sigmoid_cr(__fadd_rn(xr, hr));
    float u = sigmoid_cr(__fadd_rn(xu, hu));
    float nn = tanh_cr(__fadd_rn(xn, __fmul_rn(r, hn)));
    float h2 = __fadd_rn(__fmul_rn(__fsub_rn(1.0f, u), nn),
                         __fmul_rn(u, ldcc(H + (size_t)row * 1024 + n)));
    hv[q] = h2;
    xs[cl][i] = h2;
  }
  redstats(xs, stats);
  float mean = stats[0], rstd = stats[1];
  #pragma unroll
  for (int q = 0; q < 4; ++q) {
    int i = iq * 4 + q;
    int n = kb * 128 + 8 * i + j;
    float d = __fsub_rn(hv[q], mean);
    float h3 = __fadd_rn(__fmul_rn(__fmul_rn(d, rstd), g_gn[n]), b_gn[n]);
    stcc(H + (size_t)row * 1024 + n, h3);
    stcc(out + ((size_t)row * 64 + t) * 1024 + n, h3);
  }
}

__device__ void sample_row(const float* Yq, const float* bq2,
                           const float* Y2p, const float* bp2,
                           const float* u_post, const float* actions,
                           float* XZ, float* out, int t, int b, int prior)
{
  const size_t NOUT = 16777216ull;
  int tid = threadIdx.x;
  int d = tid >> 3, lane = tid & 7;
  const float C0 = (float)(1.0 - 0.01);
  const float C1 = (float)(0.01 / 32.0);
  const float* Y = prior ? Y2p : Yq;
  const float* bias = prior ? bp2 : bq2;

  float lg[4];
  #pragma unroll
  for (int i = 0; i < 4; ++i) {
    int col = d * 32 + lane + 8 * i;
    size_t idx = (size_t)b * 1024 + col;
    float x = __fadd_rn(__fadd_rn(ldcc(Y + idx), ldcc(Y + 262144 + idx)),
                        ldcc(Y + 524288 + idx));
    lg[i] = __fadd_rn(x, bias[col]);
  }
  float mx = fmaxf(fmaxf(lg[0], lg[1]), fmaxf(lg[2], lg[3]));
  for (int off = 4; off; off >>= 1) mx = fmaxf(mx, __shfl_xor(mx, off, 8));

  float e[4];
  #pragma unroll
  for (int i = 0; i < 4; ++i) e[i] = exp_cr(__fsub_rn(lg[i], mx));
  float ssum = e[0];
  ssum = __fadd_rn(ssum, e[1]);
  ssum = __fadd_rn(ssum, e[2]);
  ssum = __fadd_rn(ssum, e[3]);
  ssum = __fadd_rn(ssum, __shfl_xor(ssum, 1, 8));
  ssum = __fadd_rn(ssum, __shfl_xor(ssum, 2, 8));
  ssum = __fadd_rn(ssum, __shfl_xor(ssum, 4, 8));

  float p[4];
  #pragma unroll
  for (int i = 0; i < 4; ++i) {
    float pr = __fdiv_rn(e[i], ssum);
    p[i] = __fadd_rn(__fmul_rn(C0, pr), C1);
  }

  size_t ob = ((size_t)b * 64 + t) * 1024;
  if (prior) {
    #pragma unroll
    for (int i = 0; i < 4; ++i)
      stcc(out + 2 * NOUT + ob + (d * 32 + lane + 8 * i), p[i]);
    return;
  }

  float bv = -3.4e38f; int bc = 33;
  #pragma unroll
  for (int i = 0; i < 4; ++i) {
    int c = lane + 8 * i, col = d * 32 + c;
    stcc(out + 3 * NOUT + ob + col, p[i]);
    float uu = u_post[((size_t)t * 256 + b) * 1024 + col];
    float l1 = log_cr(uu);
    float v1 = -l1;
    float l2 = log_cr(v1);
    float gu = -l2;
    float lp = log_cr(p[i]);
    float val = __fadd_rn(lp, gu);
    if (val > bv) { bv = val; bc = c; }       // first max (c ascending)
  }
  for (int off = 4; off; off >>= 1) {
    float ov = __shfl_xor(bv, off, 8);
    int   oc = __shfl_xor(bc, off, 8);
    if (ov > bv || (ov == bv && oc < bc)) { bv = ov; bc = oc; }
  }
  #pragma unroll
  for (int i = 0; i < 4; ++i) {
    int c = lane + 8 * i, col = d * 32 + c;
    float zv = 0.0f;
    if (c == bc) zv = __fsub_rn(__fadd_rn(1.0f, p[i]), p[i]);
    stcc(out + NOUT + ob + col, zv);
    stcc(XZ + (size_t)b * 1040 + col, zv);
  }
  if (tid < 6 && (t + 1) < 64)
    stcc(XZ + (size_t)b * 1040 + 1024 + tid,
         actions[((size_t)b * 64 + (t + 1)) * 6 + tid]);
}

struct MegaP {
  const float *embeds, *actions, *h_init, *z_init;
  const float *W_pre, *b_pre, *g_pre, *be_pre;
  const float *W_ih, *W_hh, *b_ih, *b_hh, *g_gn, *b_gn;
  const float *Wp1, *bp1, *gp, *bpn, *Wp2, *bp2;
  const float *Wq1, *bq1, *gq, *bqn, *Wq2, *bq2;
  const float *u_post;
  float* out;
  float *H, *XZ, *PREY, *Q1A, *GX, *GH, *YQ, *Y2p, *YQ2, *XPRE, *Y1p, *P1Ap;
  unsigned* bar;
};

__global__ void bar_init_k(unsigned* bar) {
  for (int i = 0; i < 640; ++i) bar[i] = 0;
}

__global__ __launch_bounds__(256, 4) void mega_k(MegaP P)
{
  __shared__ float As[2][16][68];
  __shared__ float Bs[2][16][68];
  __shared__ float xs[64][21];
  __shared__ float stats[2];
  unsigned round = 0;

  // init H, XZ (coherent stores)
  for (int r = blockIdx.x; r < 256; r += NB) {
    int tid = threadIdx.x;
    #pragma unroll
    for (int j = 0; j < 4; ++j) {
      int n = tid + j * 256;
      stcc(P.H  + (size_t)r * 1024 + n, P.h_init[(size_t)r * 1024 + n]);
      stcc(P.XZ + (size_t)r * 1040 + n, P.z_init[(size_t)r * 1024 + n]);
    }
    if (tid < 6) stcc(P.XZ + (size_t)r * 1040 + 1024 + tid,
                      P.actions[(size_t)r * 64 * 6 + tid]);
  }
  gbar(P.bar, &round);

  GArg dummy{nullptr, 0, nullptr, 0, 0, nullptr, 0, nullptr, 0, 0};

  for (int t = 0; t < 64; ++t) {
    // A: pre(t): PREY = panels([z|a] @ W_pre^T), K=1030 (scalar staging)
    {
      GArg pre{P.XZ, 1040, P.XZ, 1040, KS, P.W_pre, 1030, P.PREY, 1024, 1030};
      run3(pre, 192, dummy, 0, dummy, 0, As, Bs);
    }
    gbar(P.bar, &round);
    // B: lnpre -> XPRE
    for (int r = blockIdx.x; r < 256; r += NB)
      ln_row<3>(P.PREY, P.b_pre, P.g_pre, P.be_pre, P.XPRE, r, xs, stats);
    gbar(P.bar, &round);
    // C: GX(t) [+ GH(0) at t=0]
    {
      GArg gx{P.XPRE, 1024, P.XPRE, 1024, KS, P.W_ih, 1024, P.GX, 3072, 1024};
      GArg gh{P.H,    1024, P.H,    1024, KS, P.W_hh, 1024, P.GH, 3072, 1024};
      if (t == 0) run3(gx, 576, gh, 576, dummy, 0, As, Bs);
      else        run3(gx, 576, dummy, 0, dummy, 0, As, Bs);
    }
    gbar(P.bar, &round);
    // D: gru -> H, hs
    for (int r = blockIdx.x; r < 256; r += NB)
      gru_row(P.GX, P.GH, P.H, P.b_ih, P.b_hh, P.g_gn, P.b_gn, P.out, t, r, xs, stats);
    gbar(P.bar, &round);
    // E: q1(t) + GH(t+1) + py1(t)
    {
      GArg q1 {P.H, 1024, P.embeds + (size_t)t * 1024, 65536, 1024,
               P.Wq1, 2048, P.YQ, 1024, 2048};
      GArg gh {P.H, 1024, P.H, 1024, KS, P.W_hh, 1024, P.GH, 3072, 1024};
      GArg py1{P.out + (size_t)t * 1024, 65536, P.out, 65536, KS,
               P.Wp1, 1024, P.Y1p, 1024, 1024};
      if (t < 63) run3(q1, 384, gh, 576, py1, 192, As, Bs);
      else        run3(q1, 384, py1, 192, dummy, 0, As, Bs);
    }
    gbar(P.bar, &round);
    // F: lnq -> Q1A ; priorLN -> P1Ap
    for (int r = blockIdx.x; r < 512; r += NB) {
      if (r < 256) ln_row<6>(P.YQ, P.bq1, P.gq, P.bqn, P.Q1A, r, xs, stats);
      else         ln_row<3>(P.Y1p, P.bp1, P.gp, P.bpn, P.P1Ap, r - 256, xs, stats);
    }
    gbar(P.bar, &round);
    // G: q2(t) + py2(t)
    {
      GArg q2 {P.Q1A,  1024, P.Q1A,  1024, KS, P.Wq2, 1024, P.YQ2, 1024, 1024};
      GArg py2{P.P1Ap, 1024, P.P1Ap, 1024, KS, P.Wp2, 1024, P.Y2p, 1024, 1024};
      run3(q2, 192, py2, 192, dummy, 0, As, Bs);
    }
    gbar(P.bar, &round);
    // H: posterior sample + prior softmax
    for (int r = blockIdx.x; r < 512; r += NB)
      sample_row(P.YQ2, P.bq2, P.Y2p, P.bp2, P.u_post, P.actions,
                 P.XZ, P.out, t, r & 255, r >> 8);
    gbar(P.bar, &round);
  }
}

extern "C" void kernel_launch(void* const* d_in, const int* in_sizes, int n_in,
                              void* d_out, int out_size, void* d_ws, size_t ws_size,
                              hipStream_t stream)
{
  MegaP P;
  P.embeds  = (const float*)d_in[0];
  P.actions = (const float*)d_in[1];
  P.h_init  = (const float*)d_in[2];
  P.z_init  = (const float*)d_in[3];
  P.W_pre   = (const float*)d_in[4];
  P.b_pre   = (const float*)d_in[5];
  P.g_pre   = (const float*)d_in[6];
  P.be_pre  = (const float*)d_in[7];
  P.W_ih    = (const float*)d_in[8];
  P.W_hh    = (const float*)d_in[9];
  P.b_ih    = (const float*)d_in[10];
  P.b_hh    = (const float*)d_in[11];
  P.g_gn    = (const float*)d_in[12];
  P.b_gn    = (const float*)d_in[13];
  P.Wp1     = (const float*)d_in[14];
  P.bp1     = (const float*)d_in[15];
  P.gp      = (const float*)d_in[16];
  P.bpn     = (const float*)d_in[17];
  P.Wp2     = (const float*)d_in[18];
  P.bp2     = (const float*)d_in[19];
  P.Wq1     = (const float*)d_in[20];
  P.bq1     = (const float*)d_in[21];
  P.gq      = (const float*)d_in[22];
  P.bqn     = (const float*)d_in[23];
  P.Wq2     = (const float*)d_in[24];
  P.bq2     = (const float*)d_in[25];
  // d_in[26] = u_prior: unused
  P.u_post  = (const float*)d_in[27];
  P.out     = (float*)d_out;

  float* W0 = (float*)d_ws;
  P.H    = W0;                    // 262144
  P.XZ   = W0 + 262144;           // 266240 (row stride 1040)
  P.PREY = W0 + 528384;           // 786432 (3 panels); alias Q1A
  P.Q1A  = P.PREY;
  P.GX   = W0 + 1314816;          // 2359296 (3 panels)
  P.GH   = W0 + 3674112;          // 2359296 (lives across step)
  P.YQ   = W0 + 6033408;          // 1572864 (6 panels); alias Y2p
  P.Y2p  = P.YQ;
  P.YQ2  = W0 + 7606272;          // 786432 (3 panels); alias XPRE
  P.XPRE = P.YQ2;
  P.Y1p  = W0 + 8392704;          // 786432 (3 panels)
  P.P1Ap = W0 + 9179136;          // 262144
  P.bar  = (unsigned*)(W0 + 9441280);   // 640 words

  hipLaunchKernelGGL(bar_init_k, dim3(1), dim3(1), 0, stream, P.bar);
  hipLaunchKernelGGL(mega_k, dim3(NB), dim3(256), 0, stream, P);
}

// Round 14
// 11558.807 us; speedup vs baseline: 4.8079x; 4.8079x over previous
//
#include <hip/hip_runtime.h>
#include <hip/hip_bf16.h>
#include <math.h>

// RSSM scan — numpy-realization f32 (frozen numerics). r14 = r10 (best passing,
// 11.15ms) + bit-exact sparse-z fusion: sample+pre+lnpre merged into one
// per-row kernel (fmaf(0,w,acc)==acc identity collapses the frozen pre-chain
// to the 32 z-nonzeros + 6 actions). 8 -> 6 launches/step. Mega-kernel line
// abandoned (r11: L2-fence evicts weights; r13: coherent ops uncacheable).

struct GArg {
  const float* A0; int lda0;
  const float* A1; int lda1;
  int kSplit;
  const float* W; int ldw;
  float* C; int N; int K;             // panel s written at C + s*256*N
};

struct LArg {
  const float* Y; int S;              // fold S panels (stride 262144)
  const float* bias; const float* g; const float* be;
  float* O;
};

__device__ __forceinline__ float exp_cr(float x)  { return (float)exp((double)x); }
__device__ __forceinline__ float log_cr(float x)  { return (float)log((double)x); }
__device__ __forceinline__ float tanh_cr(float x) { return (float)tanh((double)x); }
__device__ __forceinline__ float sigmoid_cr(float x) {
  float e = exp_cr(-x);
  float d = __fadd_rn(1.0f, e);
  return __fdiv_rn(1.0f, d);
}

// ---- 64x64 tile, 256 threads, 4x4/thread, dbuf, 3-way z-slice select ----
__global__ __launch_bounds__(256) void gemm_k(GArg g0, GArg g1, GArg g2,
                                              int z1, int z2) {
  int z = blockIdx.z;
  GArg G; int s;
  if (z < z1)      { G = g0; s = z; }
  else if (z < z2) { G = g1; s = z - z1; }
  else             { G = g2; s = z - z2; }
  int n0 = blockIdx.x * 64;
  if (n0 >= G.N) return;
  int m0 = blockIdx.y * 64;

  __shared__ float As[2][16][68];   // [buf][k][m]; reads/writes <=2-way banks
  __shared__ float Bs[2][16][68];

  int tid = threadIdx.x;
  int tx = tid & 15, ty = tid >> 4;   // compute: cols tx*4, rows ty*4
  int kq = tid & 3,  rr = tid >> 2;   // vec staging: k-quad, row 0..63

  bool vecOK = ((G.ldw & 3) == 0) && ((G.lda0 & 3) == 0) && ((G.lda1 & 3) == 0)
            && (((G.kSplit & 15) == 0) || (G.kSplit >= G.K));

  float acc[4][4];
  #pragma unroll
  for (int j = 0; j < 4; ++j)
    #pragma unroll
    for (int i = 0; i < 4; ++i) acc[j][i] = 0.0f;

  int nt = (G.K + 15) >> 4;
  int t0 = s * 24, t1 = min(nt, t0 + 24);

  float a[4], w[4];
  int useVec = 0;

  auto stage_load = [&](int kt) {
    int kb = kt * 16;
    useVec = vecOK && (kb + 16 <= G.K);
    if (useVec) {
      int k = kb + kq * 4;
      float4 av = (k < G.kSplit)
        ? *(const float4*)(G.A0 + (size_t)(m0 + rr) * G.lda0 + k)
        : *(const float4*)(G.A1 + (size_t)(m0 + rr) * G.lda1 + (k - G.kSplit));
      float4 wv = *(const float4*)(G.W + (size_t)(n0 + rr) * G.ldw + k);
      a[0] = av.x; a[1] = av.y; a[2] = av.z; a[3] = av.w;
      w[0] = wv.x; w[1] = wv.y; w[2] = wv.z; w[3] = wv.w;
    } else {
      int k = kb + tx;
      #pragma unroll
      for (int i = 0; i < 4; ++i) { a[i] = 0.0f; w[i] = 0.0f; }
      if (k < G.K) {
        if (k < G.kSplit) {
          const float* Ap = G.A0 + (size_t)(m0 + ty * 4) * G.lda0 + k;
          #pragma unroll
          for (int i = 0; i < 4; ++i) a[i] = Ap[(size_t)i * G.lda0];
        } else {
          const float* Ap = G.A1 + (size_t)(m0 + ty * 4) * G.lda1 + (k - G.kSplit);
          #pragma unroll
          for (int i = 0; i < 4; ++i) a[i] = Ap[(size_t)i * G.lda1];
        }
        const float* Wp = G.W + (size_t)(n0 + ty * 4) * G.ldw + k;
        #pragma unroll
        for (int i = 0; i < 4; ++i) w[i] = Wp[(size_t)i * G.ldw];
      }
    }
  };
  auto stage_write = [&](int b) {
    if (useVec) {
      #pragma unroll
      for (int i = 0; i < 4; ++i) {
        As[b][kq * 4 + i][rr] = a[i];    // bank (16kq+4i+rr)%32: 2-way, free
        Bs[b][kq * 4 + i][rr] = w[i];
      }
    } else {
      *(float4*)&As[b][tx][ty * 4] = make_float4(a[0], a[1], a[2], a[3]);
      *(float4*)&Bs[b][tx][ty * 4] = make_float4(w[0], w[1], w[2], w[3]);
    }
  };
  auto compute = [&](int b) {
    #pragma unroll
    for (int kk = 0; kk < 16; ++kk) {
      float4 av = *(const float4*)&As[b][kk][ty * 4];
      float4 bv = *(const float4*)&Bs[b][kk][tx * 4];
      float aa[4] = {av.x, av.y, av.z, av.w};
      float bb[4] = {bv.x, bv.y, bv.z, bv.w};
      #pragma unroll
      for (int j = 0; j < 4; ++j)
        #pragma unroll
        for (int i = 0; i < 4; ++i)
          acc[j][i] = fmaf(aa[j], bb[i], acc[j][i]);   // k-ascending chain
    }
  };

  stage_load(t0); stage_write(0); __syncthreads();
  int cur = 0;
  for (int kt = t0; kt < t1; ++kt) {
    if (kt + 1 < t1) {
      stage_load(kt + 1);
      compute(cur);
      stage_write(cur ^ 1);
      __syncthreads();
      cur ^= 1;
    } else compute(cur);
  }

  float* Cp = G.C + (size_t)s * 256 * G.N;
  #pragma unroll
  for (int j = 0; j < 4; ++j)
    *(float4*)&Cp[(size_t)(m0 + ty * 4 + j) * G.N + n0 + tx * 4] =
      make_float4(acc[j][0], acc[j][1], acc[j][2], acc[j][3]);
}

// ---- LN + SiLU, 256 thr/row, grid.y selects job; wave0 frozen reduction ----
__global__ __launch_bounds__(256) void lnsilu2_k(LArg l0, LArg l1) {
  LArg L = blockIdx.y ? l1 : l0;
  __shared__ float xs[64][20];
  __shared__ float stats[2];
  int row = blockIdx.x, tid = threadIdx.x;
  int cl = tid & 63, iq = tid >> 6;
  int kb = cl >> 3, j = cl & 7;

  float xv[4];
  #pragma unroll
  for (int q = 0; q < 4; ++q) {
    int i = iq * 4 + q;
    int n = kb * 128 + 8 * i + j;
    size_t idx = (size_t)row * 1024 + n;
    float x = L.Y[idx];
    for (int ss = 1; ss < L.S; ++ss) x = __fadd_rn(x, L.Y[(size_t)ss * 262144 + idx]);
    x = __fadd_rn(x, L.bias[n]);
    xv[q] = x;
    xs[cl][i] = x;
  }
  __syncthreads();
  if (tid < 64) {
    float r = xs[cl][0];
    #pragma unroll
    for (int i = 1; i < 16; ++i) r = __fadd_rn(r, xs[cl][i]);
    r = __fadd_rn(r, __shfl_xor(r, 1));
    r = __fadd_rn(r, __shfl_xor(r, 2));
    r = __fadd_rn(r, __shfl_xor(r, 4));
    r = __fadd_rn(r, __shfl_xor(r, 8));
    r = __fadd_rn(r, __shfl_xor(r, 16));
    r = __fadd_rn(r, __shfl_xor(r, 32));
    float mean = __fmul_rn(r, 0.0009765625f);
    float d0 = __fsub_rn(xs[cl][0], mean);
    float r2 = __fmul_rn(d0, d0);
    #pragma unroll
    for (int i = 1; i < 16; ++i) {
      float d = __fsub_rn(xs[cl][i], mean);
      r2 = __fadd_rn(r2, __fmul_rn(d, d));
    }
    r2 = __fadd_rn(r2, __shfl_xor(r2, 1));
    r2 = __fadd_rn(r2, __shfl_xor(r2, 2));
    r2 = __fadd_rn(r2, __shfl_xor(r2, 4));
    r2 = __fadd_rn(r2, __shfl_xor(r2, 8));
    r2 = __fadd_rn(r2, __shfl_xor(r2, 16));
    r2 = __fadd_rn(r2, __shfl_xor(r2, 32));
    float var = __fmul_rn(r2, 0.0009765625f);
    float sdv = __fsqrt_rn(__fadd_rn(var, (float)1e-5));
    if (cl == 0) { stats[0] = mean; stats[1] = __fdiv_rn(1.0f, sdv); }
  }
  __syncthreads();
  float mean = stats[0], rstd = stats[1];
  #pragma unroll
  for (int q = 0; q < 4; ++q) {
    int i = iq * 4 + q;
    int n = kb * 128 + 8 * i + j;
    float d = __fsub_rn(xv[q], mean);
    float t = __fmul_rn(__fmul_rn(d, rstd), L.g[n]);
    t = __fadd_rn(t, L.be[n]);
    L.O[(size_t)row * 1024 + n] = __fmul_rn(t, sigmoid_cr(t));   // silu
  }
}

// ---- GRU combine + LN, 256 thr/row; wave0 frozen reduction ----
__global__ __launch_bounds__(256) void gru256_k(
  const float* GX, const float* GH, float* H,
  const float* b_ih, const float* b_hh, const float* g_gn, const float* b_gn,
  float* out, int t)
{
  __shared__ float xs[64][20];
  __shared__ float stats[2];
  int row = blockIdx.x, tid = threadIdx.x;
  int cl = tid & 63, iq = tid >> 6;
  int kb = cl >> 3, j = cl & 7;

  float hv[4];
  #pragma unroll
  for (int q = 0; q < 4; ++q) {
    int i = iq * 4 + q;
    int n = kb * 128 + 8 * i + j;
    size_t i0 = (size_t)row * 3072 + n;
    #define FOLD3(P, off) __fadd_rn(__fadd_rn((P)[off], (P)[786432 + (off)]), (P)[1572864 + (off)])
    float xr = __fadd_rn(FOLD3(GX, i0),        b_ih[n]);
    float xu = __fadd_rn(FOLD3(GX, i0 + 1024), b_ih[n + 1024]);
    float xn = __fadd_rn(FOLD3(GX, i0 + 2048), b_ih[n + 2048]);
    float hr = __fadd_rn(FOLD3(GH, i0),        b_hh[n]);
    float hu = __fadd_rn(FOLD3(GH, i0 + 1024), b_hh[n + 1024]);
    float hn = __fadd_rn(FOLD3(GH, i0 + 2048), b_hh[n + 2048]);
    #undef FOLD3
    float r = sigmoid_cr(__fadd_rn(xr, hr));
    float u = sigmoid_cr(__fadd_rn(xu, hu));
    float nn = tanh_cr(__fadd_rn(xn, __fmul_rn(r, hn)));
    float h2 = __fadd_rn(__fmul_rn(__fsub_rn(1.0f, u), nn),
                         __fmul_rn(u, H[(size_t)row * 1024 + n]));
    hv[q] = h2;
    xs[cl][i] = h2;
  }
  __syncthreads();
  if (tid < 64) {
    float r = xs[cl][0];
    #pragma unroll
    for (int i = 1; i < 16; ++i) r = __fadd_rn(r, xs[cl][i]);
    r = __fadd_rn(r, __shfl_xor(r, 1));
    r = __fadd_rn(r, __shfl_xor(r, 2));
    r = __fadd_rn(r, __shfl_xor(r, 4));
    r = __fadd_rn(r, __shfl_xor(r, 8));
    r = __fadd_rn(r, __shfl_xor(r, 16));
    r = __fadd_rn(r, __shfl_xor(r, 32));
    float mean = __fmul_rn(r, 0.0009765625f);
    float d0 = __fsub_rn(xs[cl][0], mean);
    float r2 = __fmul_rn(d0, d0);
    #pragma unroll
    for (int i = 1; i < 16; ++i) {
      float d = __fsub_rn(xs[cl][i], mean);
      r2 = __fadd_rn(r2, __fmul_rn(d, d));
    }
    r2 = __fadd_rn(r2, __shfl_xor(r2, 1));
    r2 = __fadd_rn(r2, __shfl_xor(r2, 2));
    r2 = __fadd_rn(r2, __shfl_xor(r2, 4));
    r2 = __fadd_rn(r2, __shfl_xor(r2, 8));
    r2 = __fadd_rn(r2, __shfl_xor(r2, 16));
    r2 = __fadd_rn(r2, __shfl_xor(r2, 32));
    float var = __fmul_rn(r2, 0.0009765625f);
    float sdv = __fsqrt_rn(__fadd_rn(var, (float)1e-5));
    if (cl == 0) { stats[0] = mean; stats[1] = __fdiv_rn(1.0f, sdv); }
  }
  __syncthreads();
  float mean = stats[0], rstd = stats[1];
  #pragma unroll
  for (int q = 0; q < 4; ++q) {
    int i = iq * 4 + q;
    int n = kb * 128 + 8 * i + j;
    float d = __fsub_rn(hv[q], mean);
    float h3 = __fadd_rn(__fmul_rn(__fmul_rn(d, rstd), g_gn[n]), b_gn[n]);
    H[(size_t)row * 1024 + n] = h3;
    out[((size_t)row * 64 + t) * 1024 + n] = h3;
  }
}

// ---- fused: posterior sample (frozen) + prior softmax + sparse pre + lnpre ----
// One block per batch row. Pre chain is bit-identical to the dense 384-panel
// chain because fmaf(0,w,acc)==acc bitwise for the exact-zero z entries.
__global__ __launch_bounds__(256) void fused_k(
  const float* Yq, const float* bq2, const float* Y2p, const float* bp2,
  const float* u_post, const float* actions,
  const float* W_pre, const float* b_pre, const float* g_pre, const float* be_pre,
  float* XPRE, float* out, int t)
{
  const size_t NOUT = 16777216ull;
  __shared__ int   sidx[32];
  __shared__ float szval[32];
  __shared__ float sact[8];
  __shared__ float xs[64][20];
  __shared__ float stats[2];
  int b = blockIdx.x, tid = threadIdx.x;
  int d = tid >> 3, lane = tid & 7;
  const float C0 = (float)(1.0 - 0.01);
  const float C1 = (float)(0.01 / 32.0);
  size_t ob = ((size_t)b * 64 + t) * 1024;

  // ---- posterior sample (frozen; r10 body, minus XZ writes) ----
  {
    float lg[4];
    #pragma unroll
    for (int i = 0; i < 4; ++i) {
      int col = d * 32 + lane + 8 * i;
      size_t idx = (size_t)b * 1024 + col;
      float x = __fadd_rn(__fadd_rn(Yq[idx], Yq[262144 + idx]), Yq[524288 + idx]);
      lg[i] = __fadd_rn(x, bq2[col]);
    }
    float mx = fmaxf(fmaxf(lg[0], lg[1]), fmaxf(lg[2], lg[3]));
    for (int off = 4; off; off >>= 1) mx = fmaxf(mx, __shfl_xor(mx, off, 8));
    float e[4];
    #pragma unroll
    for (int i = 0; i < 4; ++i) e[i] = exp_cr(__fsub_rn(lg[i], mx));
    float ssum = e[0];
    ssum = __fadd_rn(ssum, e[1]);
    ssum = __fadd_rn(ssum, e[2]);
    ssum = __fadd_rn(ssum, e[3]);
    ssum = __fadd_rn(ssum, __shfl_xor(ssum, 1, 8));
    ssum = __fadd_rn(ssum, __shfl_xor(ssum, 2, 8));
    ssum = __fadd_rn(ssum, __shfl_xor(ssum, 4, 8));
    float p[4];
    #pragma unroll
    for (int i = 0; i < 4; ++i) {
      float pr = __fdiv_rn(e[i], ssum);
      p[i] = __fadd_rn(__fmul_rn(C0, pr), C1);
    }
    float bv = -3.4e38f; int bc = 33;
    #pragma unroll
    for (int i = 0; i < 4; ++i) {
      int c = lane + 8 * i, col = d * 32 + c;
      out[3 * NOUT + ob + col] = p[i];
      float uu = u_post[((size_t)t * 256 + b) * 1024 + col];
      float l1 = log_cr(uu);
      float v1 = -l1;
      float l2 = log_cr(v1);
      float gu = -l2;
      float lp = log_cr(p[i]);
      float val = __fadd_rn(lp, gu);
      if (val > bv) { bv = val; bc = c; }     // first max (c ascending)
    }
    for (int off = 4; off; off >>= 1) {
      float ov = __shfl_xor(bv, off, 8);
      int   oc = __shfl_xor(bc, off, 8);
      if (ov > bv || (ov == bv && oc < bc)) { bv = ov; bc = oc; }
    }
    #pragma unroll
    for (int i = 0; i < 4; ++i) {
      int c = lane + 8 * i, col = d * 32 + c;
      float zv = 0.0f;
      if (c == bc) { zv = __fsub_rn(__fadd_rn(1.0f, p[i]), p[i]); szval[d] = zv; }
      out[NOUT + ob + col] = zv;
    }
    if (lane == 0) sidx[d] = bc;
  }

  // ---- prior softmax (value-safe; r10 body) ----
  {
    float lg[4];
    #pragma unroll
    for (int i = 0; i < 4; ++i) {
      int col = d * 32 + lane + 8 * i;
      size_t idx = (size_t)b * 1024 + col;
      float x = __fadd_rn(__fadd_rn(Y2p[idx], Y2p[262144 + idx]), Y2p[524288 + idx]);
      lg[i] = __fadd_rn(x, bp2[col]);
    }
    float mx = fmaxf(fmaxf(lg[0], lg[1]), fmaxf(lg[2], lg[3]));
    for (int off = 4; off; off >>= 1) mx = fmaxf(mx, __shfl_xor(mx, off, 8));
    float e[4];
    #pragma unroll
    for (int i = 0; i < 4; ++i) e[i] = exp_cr(__fsub_rn(lg[i], mx));
    float ssum = e[0];
    ssum = __fadd_rn(ssum, e[1]);
    ssum = __fadd_rn(ssum, e[2]);
    ssum = __fadd_rn(ssum, e[3]);
    ssum = __fadd_rn(ssum, __shfl_xor(ssum, 1, 8));
    ssum = __fadd_rn(ssum, __shfl_xor(ssum, 2, 8));
    ssum = __fadd_rn(ssum, __shfl_xor(ssum, 4, 8));
    #pragma unroll
    for (int i = 0; i < 4; ++i) {
      int col = d * 32 + lane + 8 * i;
      float pr = __fdiv_rn(e[i], ssum);
      out[2 * NOUT + ob + col] = __fadd_rn(__fmul_rn(C0, pr), C1);
    }
  }

  if (t < 63) {
    if (tid < 6) sact[tid] = actions[((size_t)b * 64 + (t + 1)) * 6 + tid];
    __syncthreads();
    // ---- sparse pre: PREY row = z-gather chains (bit-exact) + actions ----
    int cl = tid & 63, iq = tid >> 6;
    int kb = cl >> 3, j = cl & 7;
    float xv[4];
    #pragma unroll
    for (int q = 0; q < 4; ++q) {
      int i = iq * 4 + q;
      int n = kb * 128 + 8 * i + j;
      const float* Wr = W_pre + (size_t)n * 1030;
      float p0 = 0.0f, p1 = 0.0f, p2 = 0.0f;
      #pragma unroll
      for (int dd = 0; dd < 12; ++dd)
        p0 = fmaf(szval[dd], Wr[dd * 32 + sidx[dd]], p0);     // panel 0 chain
      #pragma unroll
      for (int dd = 12; dd < 24; ++dd)
        p1 = fmaf(szval[dd], Wr[dd * 32 + sidx[dd]], p1);     // panel 1 chain
      #pragma unroll
      for (int dd = 24; dd < 32; ++dd)
        p2 = fmaf(szval[dd], Wr[dd * 32 + sidx[dd]], p2);     // panel 2 chain
      #pragma unroll
      for (int ai = 0; ai < 6; ++ai)
        p2 = fmaf(sact[ai], Wr[1024 + ai], p2);               // actions (k asc)
      float x = __fadd_rn(__fadd_rn(p0, p1), p2);             // consumer fold
      x = __fadd_rn(x, b_pre[n]);
      xv[q] = x;
      xs[cl][i] = x;
    }
    // ---- frozen LN reduction + silu (r10 lnsilu2_k body) ----
    __syncthreads();
    if (tid < 64) {
      float r = xs[cl][0];
      #pragma unroll
      for (int i = 1; i < 16; ++i) r = __fadd_rn(r, xs[cl][i]);
      r = __fadd_rn(r, __shfl_xor(r, 1));
      r = __fadd_rn(r, __shfl_xor(r, 2));
      r = __fadd_rn(r, __shfl_xor(r, 4));
      r = __fadd_rn(r, __shfl_xor(r, 8));
      r = __fadd_rn(r, __shfl_xor(r, 16));
      r = __fadd_rn(r, __shfl_xor(r, 32));
      float mean = __fmul_rn(r, 0.0009765625f);
      float d0 = __fsub_rn(xs[cl][0], mean);
      float r2 = __fmul_rn(d0, d0);
      #pragma unroll
      for (int i = 1; i < 16; ++i) {
        float dd = __fsub_rn(xs[cl][i], mean);
        r2 = __fadd_rn(r2, __fmul_rn(dd, dd));
      }
      r2 = __fadd_rn(r2, __shfl_xor(r2, 1));
      r2 = __fadd_rn(r2, __shfl_xor(r2, 2));
      r2 = __fadd_rn(r2, __shfl_xor(r2, 4));
      r2 = __fadd_rn(r2, __shfl_xor(r2, 8));
      r2 = __fadd_rn(r2, __shfl_xor(r2, 16));
      r2 = __fadd_rn(r2, __shfl_xor(r2, 32));
      float var = __fmul_rn(r2, 0.0009765625f);
      float sdv = __fsqrt_rn(__fadd_rn(var, (float)1e-5));
      if (cl == 0) { stats[0] = mean; stats[1] = __fdiv_rn(1.0f, sdv); }
    }
    __syncthreads();
    float mean = stats[0], rstd = stats[1];
    #pragma unroll
    for (int q = 0; q < 4; ++q) {
      int i = iq * 4 + q;
      int n = kb * 128 + 8 * i + j;
      float dd = __fsub_rn(xv[q], mean);
      float tt = __fmul_rn(__fmul_rn(dd, rstd), g_pre[n]);
      tt = __fadd_rn(tt, be_pre[n]);
      XPRE[(size_t)b * 1024 + n] = __fmul_rn(tt, sigmoid_cr(tt));   // silu
    }
  }
}

__global__ __launch_bounds__(256) void init_k(const float* h_init, const float* z_init,
                                              const float* actions, float* H, float* XZ)
{
  int b = blockIdx.x, tid = threadIdx.x;
  #pragma unroll
  for (int j = 0; j < 4; ++j) {
    int n = tid + j * 256;
    H [(size_t)b * 1024 + n] = h_init[(size_t)b * 1024 + n];
    XZ[(size_t)b * 1040 + n] = z_init[(size_t)b * 1024 + n];
  }
  if (tid < 6) XZ[(size_t)b * 1040 + 1024 + tid] = actions[(size_t)b * 64 * 6 + tid];
}

extern "C" void kernel_launch(void* const* d_in, const int* in_sizes, int n_in,
                              void* d_out, int out_size, void* d_ws, size_t ws_size,
                              hipStream_t stream)
{
  const float* embeds  = (const float*)d_in[0];
  const float* actions = (const float*)d_in[1];
  const float* h_init  = (const float*)d_in[2];
  const float* z_init  = (const float*)d_in[3];
  const float* W_pre   = (const float*)d_in[4];
  const float* b_pre   = (const float*)d_in[5];
  const float* g_pre   = (const float*)d_in[6];
  const float* be_pre  = (const float*)d_in[7];
  const float* W_ih    = (const float*)d_in[8];
  const float* W_hh    = (const float*)d_in[9];
  const float* b_ih    = (const float*)d_in[10];
  const float* b_hh    = (const float*)d_in[11];
  const float* g_gn    = (const float*)d_in[12];
  const float* b_gn    = (const float*)d_in[13];
  const float* Wp1     = (const float*)d_in[14];
  const float* bp1     = (const float*)d_in[15];
  const float* gp      = (const float*)d_in[16];
  const float* bpn     = (const float*)d_in[17];
  const float* Wp2     = (const float*)d_in[18];
  const float* bp2     = (const float*)d_in[19];
  const float* Wq1     = (const float*)d_in[20];
  const float* bq1     = (const float*)d_in[21];
  const float* gq      = (const float*)d_in[22];
  const float* bqn     = (const float*)d_in[23];
  const float* Wq2     = (const float*)d_in[24];
  const float* bq2     = (const float*)d_in[25];
  // d_in[26] = u_prior: unused
  const float* u_post  = (const float*)d_in[27];
  float* out           = (float*)d_out;
  const int KS = 1 << 30;   // "no split" sentinel

  // workspace: same layout as passing r10 (37.8 MB, lifetime-audited)
  float* W0   = (float*)d_ws;
  float* H    = W0;                    // 262144
  float* XZ   = W0 + 262144;           // 266240 (prefix only)
  float* PREY = W0 + 528384;           // 786432 (prefix only); alias Q1A
  float* Q1A  = PREY;
  float* GX   = W0 + 1314816;          // 2359296 (3 panels)
  float* GH   = W0 + 3674112;          // 2359296 (lives across step)
  float* YQ   = W0 + 6033408;          // 1572864 (6 panels); alias Y2p
  float* Y2p  = YQ;
  float* YQ2  = W0 + 7606272;          // 786432 (3 panels); alias XPRE
  float* XPRE = YQ2;                   //   (fused_k reads YQ2 row before writing XPRE row)
  float* Y1p  = W0 + 8392704;          // 786432 (3 panels)
  float* P1Ap = W0 + 9179136;          // 262144

  hipLaunchKernelGGL(init_k, dim3(256), dim3(256), 0, stream, h_init, z_init, actions, H, XZ);

  // prefix: pre(0) (dense, scalar path) -> lnpre -> GX(0)+GH(0)
  GArg pre0{XZ, 1040, XZ, 1040, KS, W_pre, 1030, PREY, 1024, 1030};
  hipLaunchKernelGGL(gemm_k, dim3(16, 4, 3), dim3(256), 0, stream, pre0, pre0, pre0, 3, 3);
  {
    LArg lp{PREY, 3, b_pre, g_pre, be_pre, XPRE};
    hipLaunchKernelGGL(lnsilu2_k, dim3(256, 1), dim3(256), 0, stream, lp, lp);
    GArg gx{XPRE, 1024, XPRE, 1024, KS, W_ih, 1024, GX, 3072, 1024};
    GArg gh{H,    1024, H,    1024, KS, W_hh, 1024, GH, 3072, 1024};
    hipLaunchKernelGGL(gemm_k, dim3(48, 4, 6), dim3(256), 0, stream, gx, gh, gh, 3, 6);
  }

  for (int t = 0; t < 64; ++t) {
    // L1: gru -> H(=hs[t]), out
    hipLaunchKernelGGL(gru256_k, dim3(256), dim3(256), 0, stream,
                       GX, GH, H, b_ih, b_hh, g_gn, b_gn, out, t);
    // L2: q1(t) [6] + GH(t+1) [3] + priorY1(t) [3]
    GArg q1 {H, 1024, embeds + (size_t)t * 1024, 65536, 1024, Wq1, 2048, YQ, 1024, 2048};
    GArg gh {H, 1024, H, 1024, KS, W_hh, 1024, GH, 3072, 1024};
    GArg py1{out + (size_t)t * 1024, 65536, out, 65536, KS, Wp1, 1024, Y1p, 1024, 1024};
    if (t < 63)
      hipLaunchKernelGGL(gemm_k, dim3(48, 4, 12), dim3(256), 0, stream, q1, gh, py1, 6, 9);
    else
      hipLaunchKernelGGL(gemm_k, dim3(48, 4, 9), dim3(256), 0, stream, q1, q1, py1, 6, 6);
    // L3: lnq -> Q1A ; priorLN -> P1Ap
    {
      LArg lq{YQ, 6, bq1, gq, bqn, Q1A};
      LArg lr{Y1p, 3, bp1, gp, bpn, P1Ap};
      hipLaunchKernelGGL(lnsilu2_k, dim3(256, 2), dim3(256), 0, stream, lq, lr);
    }
    // L4: q2(t) [3] + priorY2(t) [3]
    GArg q2 {Q1A,  1024, Q1A,  1024, KS, Wq2, 1024, YQ2, 1024, 1024};
    GArg py2{P1Ap, 1024, P1Ap, 1024, KS, Wp2, 1024, Y2p, 1024, 1024};
    hipLaunchKernelGGL(gemm_k, dim3(16, 4, 6), dim3(256), 0, stream, q2, q2, py2, 3, 3);
    // L5: fused posterior-sample + prior-softmax + sparse-pre + lnpre -> XPRE
    hipLaunchKernelGGL(fused_k, dim3(256), dim3(256), 0, stream,
                       YQ2, bq2, Y2p, bp2, u_post, actions,
                       W_pre, b_pre, g_pre, be_pre, XPRE, out, t);
    // L6: GX(t+1)
    if (t < 63) {
      GArg gx{XPRE, 1024, XPRE, 1024, KS, W_ih, 1024, GX, 3072, 1024};
      hipLaunchKernelGGL(gemm_k, dim3(48, 4, 3), dim3(256), 0, stream, gx, gx, gx, 3, 3);
    }
  }
}

// Round 16
// 9613.766 us; speedup vs baseline: 5.7806x; 1.2023x over previous
//
#include <hip/hip_runtime.h>
#include <hip/hip_bf16.h>
#include <math.h>

// RSSM scan — numpy-realization f32 (frozen numerics). r16 = r15 with two bug
// fixes: (1) L2 flat-grid q1 count 768->384 (phantom panels were storing zero
// tiles OOB over YQ2/Y1p); (2) W_preT moved to a dedicated region (was aliased
// under Q1A, clobbered every step). Chains bit-identical to passing r14.

struct GArg {
  const float* A0; int lda0;
  const float* A1; int lda1;
  int kSplit;
  const float* W; int ldw;
  float* C; int N; int K;             // panel s written at C + s*256*N
};

struct LArg {
  const float* Y; int S;              // fold S panels (stride 262144)
  const float* bias; const float* g; const float* be;
  float* O;
};

__device__ __forceinline__ float exp_cr(float x)  { return (float)exp((double)x); }
__device__ __forceinline__ float log_cr(float x)  { return (float)log((double)x); }
__device__ __forceinline__ float tanh_cr(float x) { return (float)tanh((double)x); }
__device__ __forceinline__ float sigmoid_cr(float x) {
  float e = exp_cr(-x);
  float d = __fadd_rn(1.0f, e);
  return __fdiv_rn(1.0f, d);
}

// ---- 64x64 tile, 256 thr, 4x4/thread, dbuf; FLAT 1-D grid, exact counts ----
__global__ __launch_bounds__(256) void gemm_k(GArg g0, GArg g1, GArg g2,
                                              int c0, int c01) {
  int l = blockIdx.x;
  GArg G;
  if (l < c0)       { G = g0; }
  else if (l < c01) { G = g1; l -= c0; }
  else              { G = g2; l -= c01; }
  int nbx = G.N >> 6;
  int per = nbx * 4;
  int s   = l / per;
  int rem = l % per;
  int m0  = (rem / nbx) * 64;
  int n0  = (rem % nbx) * 64;

  __shared__ float As[2][16][68];   // [buf][k][m]; reads/writes <=2-way banks
  __shared__ float Bs[2][16][68];

  int tid = threadIdx.x;
  int tx = tid & 15, ty = tid >> 4;   // compute: cols tx*4, rows ty*4
  int kq = tid & 3,  rr = tid >> 2;   // vec staging: k-quad, row 0..63

  bool vecOK = ((G.ldw & 3) == 0) && ((G.lda0 & 3) == 0) && ((G.lda1 & 3) == 0)
            && (((G.kSplit & 15) == 0) || (G.kSplit >= G.K));

  float acc[4][4];
  #pragma unroll
  for (int j = 0; j < 4; ++j)
    #pragma unroll
    for (int i = 0; i < 4; ++i) acc[j][i] = 0.0f;

  int nt = (G.K + 15) >> 4;
  int t0 = s * 24, t1 = min(nt, t0 + 24);

  float a[4], w[4];
  int useVec = 0;

  auto stage_load = [&](int kt) {
    int kb = kt * 16;
    useVec = vecOK && (kb + 16 <= G.K);
    if (useVec) {
      int k = kb + kq * 4;
      float4 av = (k < G.kSplit)
        ? *(const float4*)(G.A0 + (size_t)(m0 + rr) * G.lda0 + k)
        : *(const float4*)(G.A1 + (size_t)(m0 + rr) * G.lda1 + (k - G.kSplit));
      float4 wv = *(const float4*)(G.W + (size_t)(n0 + rr) * G.ldw + k);
      a[0] = av.x; a[1] = av.y; a[2] = av.z; a[3] = av.w;
      w[0] = wv.x; w[1] = wv.y; w[2] = wv.z; w[3] = wv.w;
    } else {
      int k = kb + tx;
      #pragma unroll
      for (int i = 0; i < 4; ++i) { a[i] = 0.0f; w[i] = 0.0f; }
      if (k < G.K) {
        if (k < G.kSplit) {
          const float* Ap = G.A0 + (size_t)(m0 + ty * 4) * G.lda0 + k;
          #pragma unroll
          for (int i = 0; i < 4; ++i) a[i] = Ap[(size_t)i * G.lda0];
        } else {
          const float* Ap = G.A1 + (size_t)(m0 + ty * 4) * G.lda1 + (k - G.kSplit);
          #pragma unroll
          for (int i = 0; i < 4; ++i) a[i] = Ap[(size_t)i * G.lda1];
        }
        const float* Wp = G.W + (size_t)(n0 + ty * 4) * G.ldw + k;
        #pragma unroll
        for (int i = 0; i < 4; ++i) w[i] = Wp[(size_t)i * G.ldw];
      }
    }
  };
  auto stage_write = [&](int b) {
    if (useVec) {
      #pragma unroll
      for (int i = 0; i < 4; ++i) {
        As[b][kq * 4 + i][rr] = a[i];    // bank (16kq+4i+rr)%32: 2-way, free
        Bs[b][kq * 4 + i][rr] = w[i];
      }
    } else {
      *(float4*)&As[b][tx][ty * 4] = make_float4(a[0], a[1], a[2], a[3]);
      *(float4*)&Bs[b][tx][ty * 4] = make_float4(w[0], w[1], w[2], w[3]);
    }
  };
  auto compute = [&](int b) {
    #pragma unroll
    for (int kk = 0; kk < 16; ++kk) {
      float4 av = *(const float4*)&As[b][kk][ty * 4];
      float4 bv = *(const float4*)&Bs[b][kk][tx * 4];
      float aa[4] = {av.x, av.y, av.z, av.w};
      float bb[4] = {bv.x, bv.y, bv.z, bv.w};
      #pragma unroll
      for (int j = 0; j < 4; ++j)
        #pragma unroll
        for (int i = 0; i < 4; ++i)
          acc[j][i] = fmaf(aa[j], bb[i], acc[j][i]);   // k-ascending chain
    }
  };

  stage_load(t0); stage_write(0); __syncthreads();
  int cur = 0;
  for (int kt = t0; kt < t1; ++kt) {
    if (kt + 1 < t1) {
      stage_load(kt + 1);
      compute(cur);
      stage_write(cur ^ 1);
      __syncthreads();
      cur ^= 1;
    } else compute(cur);
  }

  float* Cp = G.C + (size_t)s * 256 * G.N;
  #pragma unroll
  for (int j = 0; j < 4; ++j)
    *(float4*)&Cp[(size_t)(m0 + ty * 4 + j) * G.N + n0 + tx * 4] =
      make_float4(acc[j][0], acc[j][1], acc[j][2], acc[j][3]);
}

// ---- LN + SiLU, 256 thr/row, grid.y selects job; wave0 frozen reduction ----
__global__ __launch_bounds__(256) void lnsilu2_k(LArg l0, LArg l1) {
  LArg L = blockIdx.y ? l1 : l0;
  __shared__ float xs[64][20];
  __shared__ float stats[2];
  int row = blockIdx.x, tid = threadIdx.x;
  int cl = tid & 63, iq = tid >> 6;
  int kb = cl >> 3, j = cl & 7;

  float xv[4];
  #pragma unroll
  for (int q = 0; q < 4; ++q) {
    int i = iq * 4 + q;
    int n = kb * 128 + 8 * i + j;
    size_t idx = (size_t)row * 1024 + n;
    float x = L.Y[idx];
    for (int ss = 1; ss < L.S; ++ss) x = __fadd_rn(x, L.Y[(size_t)ss * 262144 + idx]);
    x = __fadd_rn(x, L.bias[n]);
    xv[q] = x;
    xs[cl][i] = x;
  }
  __syncthreads();
  if (tid < 64) {
    float r = xs[cl][0];
    #pragma unroll
    for (int i = 1; i < 16; ++i) r = __fadd_rn(r, xs[cl][i]);
    r = __fadd_rn(r, __shfl_xor(r, 1));
    r = __fadd_rn(r, __shfl_xor(r, 2));
    r = __fadd_rn(r, __shfl_xor(r, 4));
    r = __fadd_rn(r, __shfl_xor(r, 8));
    r = __fadd_rn(r, __shfl_xor(r, 16));
    r = __fadd_rn(r, __shfl_xor(r, 32));
    float mean = __fmul_rn(r, 0.0009765625f);
    float d0 = __fsub_rn(xs[cl][0], mean);
    float r2 = __fmul_rn(d0, d0);
    #pragma unroll
    for (int i = 1; i < 16; ++i) {
      float d = __fsub_rn(xs[cl][i], mean);
      r2 = __fadd_rn(r2, __fmul_rn(d, d));
    }
    r2 = __fadd_rn(r2, __shfl_xor(r2, 1));
    r2 = __fadd_rn(r2, __shfl_xor(r2, 2));
    r2 = __fadd_rn(r2, __shfl_xor(r2, 4));
    r2 = __fadd_rn(r2, __shfl_xor(r2, 8));
    r2 = __fadd_rn(r2, __shfl_xor(r2, 16));
    r2 = __fadd_rn(r2, __shfl_xor(r2, 32));
    float var = __fmul_rn(r2, 0.0009765625f);
    float sdv = __fsqrt_rn(__fadd_rn(var, (float)1e-5));
    if (cl == 0) { stats[0] = mean; stats[1] = __fdiv_rn(1.0f, sdv); }
  }
  __syncthreads();
  float mean = stats[0], rstd = stats[1];
  #pragma unroll
  for (int q = 0; q < 4; ++q) {
    int i = iq * 4 + q;
    int n = kb * 128 + 8 * i + j;
    float d = __fsub_rn(xv[q], mean);
    float t = __fmul_rn(__fmul_rn(d, rstd), L.g[n]);
    t = __fadd_rn(t, L.be[n]);
    L.O[(size_t)row * 1024 + n] = __fmul_rn(t, sigmoid_cr(t));   // silu
  }
}

// ---- GRU combine + LN, 256 thr/row; wave0 frozen reduction ----
__global__ __launch_bounds__(256) void gru256_k(
  const float* GX, const float* GH, float* H,
  const float* b_ih, const float* b_hh, const float* g_gn, const float* b_gn,
  float* out, int t)
{
  __shared__ float xs[64][20];
  __shared__ float stats[2];
  int row = blockIdx.x, tid = threadIdx.x;
  int cl = tid & 63, iq = tid >> 6;
  int kb = cl >> 3, j = cl & 7;

  float hv[4];
  #pragma unroll
  for (int q = 0; q < 4; ++q) {
    int i = iq * 4 + q;
    int n = kb * 128 + 8 * i + j;
    size_t i0 = (size_t)row * 3072 + n;
    #define FOLD3(P, off) __fadd_rn(__fadd_rn((P)[off], (P)[786432 + (off)]), (P)[1572864 + (off)])
    float xr = __fadd_rn(FOLD3(GX, i0),        b_ih[n]);
    float xu = __fadd_rn(FOLD3(GX, i0 + 1024), b_ih[n + 1024]);
    float xn = __fadd_rn(FOLD3(GX, i0 + 2048), b_ih[n + 2048]);
    float hr = __fadd_rn(FOLD3(GH, i0),        b_hh[n]);
    float hu = __fadd_rn(FOLD3(GH, i0 + 1024), b_hh[n + 1024]);
    float hn = __fadd_rn(FOLD3(GH, i0 + 2048), b_hh[n + 2048]);
    #undef FOLD3
    float r = sigmoid_cr(__fadd_rn(xr, hr));
    float u = sigmoid_cr(__fadd_rn(xu, hu));
    float nn = tanh_cr(__fadd_rn(xn, __fmul_rn(r, hn)));
    float h2 = __fadd_rn(__fmul_rn(__fsub_rn(1.0f, u), nn),
                         __fmul_rn(u, H[(size_t)row * 1024 + n]));
    hv[q] = h2;
    xs[cl][i] = h2;
  }
  __syncthreads();
  if (tid < 64) {
    float r = xs[cl][0];
    #pragma unroll
    for (int i = 1; i < 16; ++i) r = __fadd_rn(r, xs[cl][i]);
    r = __fadd_rn(r, __shfl_xor(r, 1));
    r = __fadd_rn(r, __shfl_xor(r, 2));
    r = __fadd_rn(r, __shfl_xor(r, 4));
    r = __fadd_rn(r, __shfl_xor(r, 8));
    r = __fadd_rn(r, __shfl_xor(r, 16));
    r = __fadd_rn(r, __shfl_xor(r, 32));
    float mean = __fmul_rn(r, 0.0009765625f);
    float d0 = __fsub_rn(xs[cl][0], mean);
    float r2 = __fmul_rn(d0, d0);
    #pragma unroll
    for (int i = 1; i < 16; ++i) {
      float d = __fsub_rn(xs[cl][i], mean);
      r2 = __fadd_rn(r2, __fmul_rn(d, d));
    }
    r2 = __fadd_rn(r2, __shfl_xor(r2, 1));
    r2 = __fadd_rn(r2, __shfl_xor(r2, 2));
    r2 = __fadd_rn(r2, __shfl_xor(r2, 4));
    r2 = __fadd_rn(r2, __shfl_xor(r2, 8));
    r2 = __fadd_rn(r2, __shfl_xor(r2, 16));
    r2 = __fadd_rn(r2, __shfl_xor(r2, 32));
    float var = __fmul_rn(r2, 0.0009765625f);
    float sdv = __fsqrt_rn(__fadd_rn(var, (float)1e-5));
    if (cl == 0) { stats[0] = mean; stats[1] = __fdiv_rn(1.0f, sdv); }
  }
  __syncthreads();
  float mean = stats[0], rstd = stats[1];
  #pragma unroll
  for (int q = 0; q < 4; ++q) {
    int i = iq * 4 + q;
    int n = kb * 128 + 8 * i + j;
    float d = __fsub_rn(hv[q], mean);
    float h3 = __fadd_rn(__fmul_rn(__fmul_rn(d, rstd), g_gn[n]), b_gn[n]);
    H[(size_t)row * 1024 + n] = h3;
    out[((size_t)row * 64 + t) * 1024 + n] = h3;
  }
}

// ---- one-time transpose of W_pre's z-columns: W_preT[k][n] = W_pre[n][k] ----
__global__ __launch_bounds__(256) void trans_k(const float* W_pre, float* W_preT)
{
  int k = blockIdx.x, tid = threadIdx.x;
  #pragma unroll
  for (int q = 0; q < 4; ++q) {
    int n = tid + q * 256;
    W_preT[(size_t)k * 1024 + n] = W_pre[(size_t)n * 1030 + k];
  }
}

// ---- fused: posterior sample (frozen) + prior softmax + sparse pre + lnpre ----
__global__ __launch_bounds__(256) void fused_k(
  const float* Yq, const float* bq2, const float* Y2p, const float* bp2,
  const float* u_post, const float* actions,
  const float* W_pre, const float* W_preT,
  const float* b_pre, const float* g_pre, const float* be_pre,
  float* XPRE, float* out, int t)
{
  const size_t NOUT = 16777216ull;
  __shared__ int   sidx[32];
  __shared__ float szval[32];
  __shared__ float sact[8];
  __shared__ float xs[64][20];
  __shared__ float stats[2];
  int b = blockIdx.x, tid = threadIdx.x;
  int d = tid >> 3, lane = tid & 7;
  const float C0 = (float)(1.0 - 0.01);
  const float C1 = (float)(0.01 / 32.0);
  size_t ob = ((size_t)b * 64 + t) * 1024;

  // ---- posterior sample (frozen) ----
  {
    float lg[4];
    #pragma unroll
    for (int i = 0; i < 4; ++i) {
      int col = d * 32 + lane + 8 * i;
      size_t idx = (size_t)b * 1024 + col;
      float x = __fadd_rn(__fadd_rn(Yq[idx], Yq[262144 + idx]), Yq[524288 + idx]);
      lg[i] = __fadd_rn(x, bq2[col]);
    }
    float mx = fmaxf(fmaxf(lg[0], lg[1]), fmaxf(lg[2], lg[3]));
    for (int off = 4; off; off >>= 1) mx = fmaxf(mx, __shfl_xor(mx, off, 8));
    float e[4];
    #pragma unroll
    for (int i = 0; i < 4; ++i) e[i] = exp_cr(__fsub_rn(lg[i], mx));
    float ssum = e[0];
    ssum = __fadd_rn(ssum, e[1]);
    ssum = __fadd_rn(ssum, e[2]);
    ssum = __fadd_rn(ssum, e[3]);
    ssum = __fadd_rn(ssum, __shfl_xor(ssum, 1, 8));
    ssum = __fadd_rn(ssum, __shfl_xor(ssum, 2, 8));
    ssum = __fadd_rn(ssum, __shfl_xor(ssum, 4, 8));
    float p[4];
    #pragma unroll
    for (int i = 0; i < 4; ++i) {
      float pr = __fdiv_rn(e[i], ssum);
      p[i] = __fadd_rn(__fmul_rn(C0, pr), C1);
    }
    float bv = -3.4e38f; int bc = 33;
    #pragma unroll
    for (int i = 0; i < 4; ++i) {
      int c = lane + 8 * i, col = d * 32 + c;
      out[3 * NOUT + ob + col] = p[i];
      float uu = u_post[((size_t)t * 256 + b) * 1024 + col];
      float l1 = log_cr(uu);
      float v1 = -l1;
      float l2 = log_cr(v1);
      float gu = -l2;
      float lp = log_cr(p[i]);
      float val = __fadd_rn(lp, gu);
      if (val > bv) { bv = val; bc = c; }     // first max (c ascending)
    }
    for (int off = 4; off; off >>= 1) {
      float ov = __shfl_xor(bv, off, 8);
      int   oc = __shfl_xor(bc, off, 8);
      if (ov > bv || (ov == bv && oc < bc)) { bv = ov; bc = oc; }
    }
    #pragma unroll
    for (int i = 0; i < 4; ++i) {
      int c = lane + 8 * i, col = d * 32 + c;
      float zv = 0.0f;
      if (c == bc) { zv = __fsub_rn(__fadd_rn(1.0f, p[i]), p[i]); szval[d] = zv; }
      out[NOUT + ob + col] = zv;
    }
    if (lane == 0) sidx[d] = bc;
  }

  // ---- prior softmax (value-safe) ----
  {
    float lg[4];
    #pragma unroll
    for (int i = 0; i < 4; ++i) {
      int col = d * 32 + lane + 8 * i;
      size_t idx = (size_t)b * 1024 + col;
      float x = __fadd_rn(__fadd_rn(Y2p[idx], Y2p[262144 + idx]), Y2p[524288 + idx]);
      lg[i] = __fadd_rn(x, bp2[col]);
    }
    float mx = fmaxf(fmaxf(lg[0], lg[1]), fmaxf(lg[2], lg[3]));
    for (int off = 4; off; off >>= 1) mx = fmaxf(mx, __shfl_xor(mx, off, 8));
    float e[4];
    #pragma unroll
    for (int i = 0; i < 4; ++i) e[i] = exp_cr(__fsub_rn(lg[i], mx));
    float ssum = e[0];
    ssum = __fadd_rn(ssum, e[1]);
    ssum = __fadd_rn(ssum, e[2]);
    ssum = __fadd_rn(ssum, e[3]);
    ssum = __fadd_rn(ssum, __shfl_xor(ssum, 1, 8));
    ssum = __fadd_rn(ssum, __shfl_xor(ssum, 2, 8));
    ssum = __fadd_rn(ssum, __shfl_xor(ssum, 4, 8));
    #pragma unroll
    for (int i = 0; i < 4; ++i) {
      int col = d * 32 + lane + 8 * i;
      float pr = __fdiv_rn(e[i], ssum);
      out[2 * NOUT + ob + col] = __fadd_rn(__fmul_rn(C0, pr), C1);
    }
  }

  if (t < 63) {
    if (tid < 6) sact[tid] = actions[((size_t)b * 64 + (t + 1)) * 6 + tid];
    __syncthreads();
    // ---- sparse pre via W_preT (coalesced); chains bit-exact ----
    int cl = tid & 63, iq = tid >> 6;
    int kb = cl >> 3, j = cl & 7;
    float xv[4];
    #pragma unroll
    for (int q = 0; q < 4; ++q) {
      int i = iq * 4 + q;
      int n = kb * 128 + 8 * i + j;
      float p0 = 0.0f, p1 = 0.0f, p2 = 0.0f;
      #pragma unroll
      for (int dd = 0; dd < 12; ++dd)
        p0 = fmaf(szval[dd], W_preT[(size_t)(dd * 32 + sidx[dd]) * 1024 + n], p0);
      #pragma unroll
      for (int dd = 12; dd < 24; ++dd)
        p1 = fmaf(szval[dd], W_preT[(size_t)(dd * 32 + sidx[dd]) * 1024 + n], p1);
      #pragma unroll
      for (int dd = 24; dd < 32; ++dd)
        p2 = fmaf(szval[dd], W_preT[(size_t)(dd * 32 + sidx[dd]) * 1024 + n], p2);
      const float* Wr = W_pre + (size_t)n * 1030;
      #pragma unroll
      for (int ai = 0; ai < 6; ++ai)
        p2 = fmaf(sact[ai], Wr[1024 + ai], p2);               // actions (k asc)
      float x = __fadd_rn(__fadd_rn(p0, p1), p2);             // consumer fold
      x = __fadd_rn(x, b_pre[n]);
      xv[q] = x;
      xs[cl][i] = x;
    }
    __syncthreads();
    if (tid < 64) {
      float r = xs[cl][0];
      #pragma unroll
      for (int i = 1; i < 16; ++i) r = __fadd_rn(r, xs[cl][i]);
      r = __fadd_rn(r, __shfl_xor(r, 1));
      r = __fadd_rn(r, __shfl_xor(r, 2));
      r = __fadd_rn(r, __shfl_xor(r, 4));
      r = __fadd_rn(r, __shfl_xor(r, 8));
      r = __fadd_rn(r, __shfl_xor(r, 16));
      r = __fadd_rn(r, __shfl_xor(r, 32));
      float mean = __fmul_rn(r, 0.0009765625f);
      float d0 = __fsub_rn(xs[cl][0], mean);
      float r2 = __fmul_rn(d0, d0);
      #pragma unroll
      for (int i = 1; i < 16; ++i) {
        float dd = __fsub_rn(xs[cl][i], mean);
        r2 = __fadd_rn(r2, __fmul_rn(dd, dd));
      }
      r2 = __fadd_rn(r2, __shfl_xor(r2, 1));
      r2 = __fadd_rn(r2, __shfl_xor(r2, 2));
      r2 = __fadd_rn(r2, __shfl_xor(r2, 4));
      r2 = __fadd_rn(r2, __shfl_xor(r2, 8));
      r2 = __fadd_rn(r2, __shfl_xor(r2, 16));
      r2 = __fadd_rn(r2, __shfl_xor(r2, 32));
      float var = __fmul_rn(r2, 0.0009765625f);
      float sdv = __fsqrt_rn(__fadd_rn(var, (float)1e-5));
      if (cl == 0) { stats[0] = mean; stats[1] = __fdiv_rn(1.0f, sdv); }
    }
    __syncthreads();
    float mean = stats[0], rstd = stats[1];
    #pragma unroll
    for (int q = 0; q < 4; ++q) {
      int i = iq * 4 + q;
      int n = kb * 128 + 8 * i + j;
      float dd = __fsub_rn(xv[q], mean);
      float tt = __fmul_rn(__fmul_rn(dd, rstd), g_pre[n]);
      tt = __fadd_rn(tt, be_pre[n]);
      XPRE[(size_t)b * 1024 + n] = __fmul_rn(tt, sigmoid_cr(tt));   // silu
    }
  }
}

__global__ __launch_bounds__(256) void init_k(const float* h_init, const float* z_init,
                                              const float* actions, float* H, float* XZ)
{
  int b = blockIdx.x, tid = threadIdx.x;
  #pragma unroll
  for (int j = 0; j < 4; ++j) {
    int n = tid + j * 256;
    H [(size_t)b * 1024 + n] = h_init[(size_t)b * 1024 + n];
    XZ[(size_t)b * 1040 + n] = z_init[(size_t)b * 1024 + n];
  }
  if (tid < 6) XZ[(size_t)b * 1040 + 1024 + tid] = actions[(size_t)b * 64 * 6 + tid];
}

extern "C" void kernel_launch(void* const* d_in, const int* in_sizes, int n_in,
                              void* d_out, int out_size, void* d_ws, size_t ws_size,
                              hipStream_t stream)
{
  const float* embeds  = (const float*)d_in[0];
  const float* actions = (const float*)d_in[1];
  const float* h_init  = (const float*)d_in[2];
  const float* z_init  = (const float*)d_in[3];
  const float* W_pre   = (const float*)d_in[4];
  const float* b_pre   = (const float*)d_in[5];
  const float* g_pre   = (const float*)d_in[6];
  const float* be_pre  = (const float*)d_in[7];
  const float* W_ih    = (const float*)d_in[8];
  const float* W_hh    = (const float*)d_in[9];
  const float* b_ih    = (const float*)d_in[10];
  const float* b_hh    = (const float*)d_in[11];
  const float* g_gn    = (const float*)d_in[12];
  const float* b_gn    = (const float*)d_in[13];
  const float* Wp1     = (const float*)d_in[14];
  const float* bp1     = (const float*)d_in[15];
  const float* gp      = (const float*)d_in[16];
  const float* bpn     = (const float*)d_in[17];
  const float* Wp2     = (const float*)d_in[18];
  const float* bp2     = (const float*)d_in[19];
  const float* Wq1     = (const float*)d_in[20];
  const float* bq1     = (const float*)d_in[21];
  const float* gq      = (const float*)d_in[22];
  const float* bqn     = (const float*)d_in[23];
  const float* Wq2     = (const float*)d_in[24];
  const float* bq2     = (const float*)d_in[25];
  // d_in[26] = u_prior: unused
  const float* u_post  = (const float*)d_in[27];
  float* out           = (float*)d_out;
  const int KS = 1 << 30;   // "no split" sentinel

  // repacked workspace, 9,699,328 floats = 38.8 MB; WpT has a DEDICATED
  // region (nothing writes it after trans_k). Prefix-only XZ/PREY alias
  // regions that are dead during the prefix.
  float* W0   = (float*)d_ws;
  float* H    = W0;                    // 262144  [live always]
  float* Q1A  = W0 + 262144;           // 262144  [L3 -> L4]
  float* GX   = W0 + 524288;           // 2359296 [L6 -> L1]
  float* GH   = W0 + 2883584;          // 2359296 [L2 -> next L1]
  float* YQ   = W0 + 5242880;          // 1572864 [L2 -> L3]; alias Y2p, PREY
  float* Y2p  = YQ;                    //         [L4 -> L5]
  float* PREY = YQ;                    //         [prefix only]
  float* YQ2  = W0 + 6815744;          // 786432  [L4 -> L5]; alias XPRE
  float* XPRE = YQ2;                   //         [L5 -> L6]
  float* Y1p  = W0 + 7602176;          // 786432  [L2 -> L3]
  float* P1Ap = W0 + 8388608;          // 262144  [L3 -> L4]
  float* WpT  = W0 + 8650752;          // 1048576 [trans_k -> read-only]
  float* XZ   = WpT;                   // 266240  [prefix only, pre-trans_k]

  hipLaunchKernelGGL(init_k, dim3(256), dim3(256), 0, stream, h_init, z_init, actions, H, XZ);

  // prefix: pre(0) dense -> lnpre -> GX(0)+GH(0); then W_preT transpose
  GArg pre0{XZ, 1040, XZ, 1040, KS, W_pre, 1030, PREY, 1024, 1030};
  hipLaunchKernelGGL(gemm_k, dim3(192), dim3(256), 0, stream, pre0, pre0, pre0, 192, 192);
  {
    LArg lp{PREY, 3, b_pre, g_pre, be_pre, XPRE};
    hipLaunchKernelGGL(lnsilu2_k, dim3(256, 1), dim3(256), 0, stream, lp, lp);
    GArg gx{XPRE, 1024, XPRE, 1024, KS, W_ih, 1024, GX, 3072, 1024};
    GArg gh{H,    1024, H,    1024, KS, W_hh, 1024, GH, 3072, 1024};
    hipLaunchKernelGGL(gemm_k, dim3(1152), dim3(256), 0, stream, gx, gh, gh, 576, 1152);
  }
  hipLaunchKernelGGL(trans_k, dim3(1024), dim3(256), 0, stream, W_pre, WpT);

  for (int t = 0; t < 64; ++t) {
    // L1: gru -> H(=hs[t]), out
    hipLaunchKernelGGL(gru256_k, dim3(256), dim3(256), 0, stream,
                       GX, GH, H, b_ih, b_hh, g_gn, b_gn, out, t);
    // L2: q1(t) [6x64=384] + GH(t+1) [3x192=576] + priorY1(t) [3x64=192]
    GArg q1 {H, 1024, embeds + (size_t)t * 1024, 65536, 1024, Wq1, 2048, YQ, 1024, 2048};
    GArg gh {H, 1024, H, 1024, KS, W_hh, 1024, GH, 3072, 1024};
    GArg py1{out + (size_t)t * 1024, 65536, out, 65536, KS, Wp1, 1024, Y1p, 1024, 1024};
    if (t < 63)
      hipLaunchKernelGGL(gemm_k, dim3(1152), dim3(256), 0, stream, q1, gh, py1, 384, 960);
    else
      hipLaunchKernelGGL(gemm_k, dim3(576), dim3(256), 0, stream, q1, q1, py1, 384, 384);
    // L3: lnq -> Q1A ; priorLN -> P1Ap
    {
      LArg lq{YQ, 6, bq1, gq, bqn, Q1A};
      LArg lr{Y1p, 3, bp1, gp, bpn, P1Ap};
      hipLaunchKernelGGL(lnsilu2_k, dim3(256, 2), dim3(256), 0, stream, lq, lr);
    }
    // L4: q2(t) [192] + priorY2(t) [192]
    GArg q2 {Q1A,  1024, Q1A,  1024, KS, Wq2, 1024, YQ2, 1024, 1024};
    GArg py2{P1Ap, 1024, P1Ap, 1024, KS, Wp2, 1024, Y2p, 1024, 1024};
    hipLaunchKernelGGL(gemm_k, dim3(384), dim3(256), 0, stream, q2, py2, py2, 192, 384);
    // L5: fused posterior-sample + prior-softmax + sparse-pre + lnpre -> XPRE
    hipLaunchKernelGGL(fused_k, dim3(256), dim3(256), 0, stream,
                       YQ2, bq2, Y2p, bp2, u_post, actions,
                       W_pre, WpT, b_pre, g_pre, be_pre, XPRE, out, t);
    // L6: GX(t+1) [3x192=576]
    if (t < 63) {
      GArg gx{XPRE, 1024, XPRE, 1024, KS, W_ih, 1024, GX, 3072, 1024};
      hipLaunchKernelGGL(gemm_k, dim3(576), dim3(256), 0, stream, gx, gx, gx, 576, 576);
    }
  }
}